// Round 3
// baseline (13072.507 us; speedup 1.0000x reference)
//
#include <hip/hip_runtime.h>

#define DI __device__ __forceinline__

static constexpr int Bb  = 32;
static constexpr int Tt  = 12;
static constexpr int FIN = 16;
static constexpr int NN  = 2048;
static constexpr int HID = 3;
static constexpr int M1  = Bb*Tt*FIN;    // 6144
static constexpr int M2  = Bb*Tt*32;     // 12288

DI float b2f(unsigned short u){
  unsigned int v = ((unsigned int)u) << 16;
  float f; __builtin_memcpy(&f, &v, 4); return f;
}
DI unsigned short f2b(float f){
  unsigned int v; __builtin_memcpy(&v, &f, 4);
  v = v + 0x7FFFu + ((v >> 16) & 1u);
  return (unsigned short)(v >> 16);
}
// dtype-agnostic load: flag=1 -> buffer is bf16 (ushort), flag=0 -> float32
DI float ld(const void* p, size_t i, int flag){
  return flag ? b2f(((const unsigned short*)p)[i]) : ((const float*)p)[i];
}

// ---------------- dtype sniff: even-indexed ushorts of fp32 data are mantissa bits
// -> random bf16 exponents -> huge values. bf16 data stays small.
__global__ void k_sniff(const unsigned short* __restrict__ x, int* __restrict__ flag){
  int tid = threadIdx.x;                      // 64 threads
  float v = b2f(x[tid*2]);
  int bad = (!(v == v)) || (fabsf(v) > 1e6f);
  unsigned long long m = __ballot(bad);
  if (tid == 0) *flag = (m == 0ull) ? 1 : 0;
}

// ---------------- SE attention ----------------
__global__ void k_att_mean(const void* __restrict__ x, float* __restrict__ att0,
                           const int* __restrict__ flagp){
  int flag = *flagp;
  int bt = blockIdx.x; int tid = threadIdx.x;
  size_t base = (size_t)bt * FIN * NN;
  float s = 0.f;
  for (int i = tid; i < FIN*NN; i += 256) s += ld(x, base + i, flag);
  for (int off = 32; off; off >>= 1) s += __shfl_down(s, off);
  __shared__ float red[4];
  if ((tid & 63) == 0) red[tid >> 6] = s;
  __syncthreads();
  if (tid == 0) att0[bt] = (red[0]+red[1]+red[2]+red[3]) * (1.f / (FIN*NN));
}

__global__ void k_att_mlp(const float* __restrict__ att0,
                          const void* __restrict__ m1w, const void* __restrict__ m1b,
                          const void* __restrict__ m2w, const void* __restrict__ m2b,
                          float* __restrict__ att, const int* __restrict__ flagp){
  int flag = *flagp;
  int b = threadIdx.x;
  if (b >= Bb) return;
  float a[Tt];
  #pragma unroll
  for (int t = 0; t < Tt; ++t) a[t] = att0[b*Tt + t];
  float h[HID];
  #pragma unroll
  for (int j = 0; j < HID; ++j){
    float s = ld(m1b, j, flag);
    #pragma unroll
    for (int t = 0; t < Tt; ++t) s += a[t] * ld(m1w, j*Tt + t, flag);
    h[j] = s > 0.f ? s : 0.f;
  }
  #pragma unroll
  for (int t = 0; t < Tt; ++t){
    float s = ld(m2b, t, flag);
    #pragma unroll
    for (int j = 0; j < HID; ++j) s += h[j] * ld(m2w, t*HID + j, flag);
    att[b*Tt + t] = 1.f / (1.f + expf(-s));
  }
}

// ---------------- VALU GEMM: z[k][row][n] = sum_m A[row][m] * cheb[k][m][n]
// ASRC=0: A = x * att[bt] (dtype per flag). ASRC=1: A = X1 (always bf16).
// 16 rows x 256 cols per block, 64-wide m panels staged in LDS as fp32.
template <int ASRC>
__global__ __launch_bounds__(256, 4)
void k_gemm_v(const void* __restrict__ Asrc, const float* __restrict__ att,
              const void* __restrict__ cheb, unsigned short* __restrict__ z,
              int M, int n0, int CH, const int* __restrict__ flagp){
  int flag = *flagp;
  __shared__ float As[16*64];
  int tid  = threadIdx.x;
  int k    = blockIdx.z;
  int row0 = blockIdx.x * 16;
  int zcol = blockIdx.y * 256 + tid;     // chunk-local col
  int col  = n0 + zcol;                  // global col
  const unsigned short* chU = (const unsigned short*)cheb;
  const float*          chF = (const float*)cheb;
  size_t cbase = (size_t)k * NN * NN + col;

  float acc[16];
  #pragma unroll
  for (int r = 0; r < 16; ++r) acc[r] = 0.f;

  for (int m0 = 0; m0 < NN; m0 += 64){
    // stage A panel (16 rows x 64 m)
    #pragma unroll
    for (int j = 0; j < 4; ++j){
      int idx = tid + j*256;             // idx = r*64 + mm
      int r = idx >> 6, mm = idx & 63;
      size_t a = (size_t)(row0 + r)*NN + m0 + mm;
      float v;
      if (ASRC == 0) v = ld(Asrc, a, flag) * att[(row0 + r) >> 4];
      else           v = b2f(((const unsigned short*)Asrc)[a]);
      As[idx] = v;
    }
    __syncthreads();
    if (flag){
      for (int mm = 0; mm < 64; ++mm){
        float c = b2f(chU[cbase + (size_t)(m0 + mm)*NN]);
        #pragma unroll
        for (int r = 0; r < 16; ++r) acc[r] += As[r*64 + mm] * c;
      }
    } else {
      for (int mm = 0; mm < 64; ++mm){
        float c = chF[cbase + (size_t)(m0 + mm)*NN];
        #pragma unroll
        for (int r = 0; r < 16; ++r) acc[r] += As[r*64 + mm] * c;
      }
    }
    __syncthreads();
  }
  #pragma unroll
  for (int r = 0; r < 16; ++r)
    z[((size_t)(k*M + row0 + r))*CH + zcol] = f2b(acc[r]);
}

// ---------------- theta mixing: xg[bt][o][n] = relu(sum_{k,f} theta[k][f][o]*z[k][bt*F+f][n])
template <int F>
__global__ void k_mix(const unsigned short* __restrict__ z,
                      const void* __restrict__ theta,
                      unsigned short* __restrict__ xg,
                      int n0, int CH, const int* __restrict__ flagp){
  int flag = *flagp;
  __shared__ float th[3*F*32];
  int tid = threadIdx.x;
  int bt  = blockIdx.x;
  int colb = blockIdx.y * 128;
  for (int i = tid; i < 3*F*32; i += 256) th[i] = ld(theta, i, flag);
  __syncthreads();
  int col = tid & 127, oh = tid >> 7;
  const int M = 384*F;
  float acc[16];
  #pragma unroll
  for (int o = 0; o < 16; ++o) acc[o] = 0.f;
  for (int k = 0; k < 3; ++k)
    for (int f = 0; f < F; ++f){
      float zv = b2f(z[((size_t)(k*M + bt*F + f))*CH + colb + col]);
      const float* tp = &th[(k*F + f)*32 + oh*16];
      #pragma unroll
      for (int o = 0; o < 16; ++o) acc[o] += zv * tp[o];
    }
  #pragma unroll
  for (int o = 0; o < 16; ++o){
    float v = acc[o]; v = v > 0.f ? v : 0.f;
    xg[((size_t)(bt*32 + oh*16 + o))*NN + n0 + colb + col] = f2b(v);
  }
}

// ---------------- temporal conv 1 (kernel (1,2), wrap-pad, relu) ----------------
__global__ void k_tconv1(const unsigned short* __restrict__ xin,   // [bt*32+i][NN] bf16
                         const void* __restrict__ wgt, const void* __restrict__ bias,
                         unsigned short* __restrict__ yout, const int* __restrict__ flagp){
  int flag = *flagp;
  __shared__ float wl[32*32*2];
  __shared__ float bl[32];
  int tid = threadIdx.x;
  for (int i = tid; i < 2048; i += 256) wl[i] = ld(wgt, i, flag);
  if (tid < 32) bl[tid] = ld(bias, tid, flag);
  __syncthreads();
  int bt = blockIdx.x, b = bt / 12, t = bt % 12;
  int c = (t == 0) ? 10 : (t - 1);
  int n = blockIdx.y*256 + tid;
  const unsigned short* p0 = xin + ((size_t)(b*12 + c  )*32)*NN + n;
  const unsigned short* p1 = xin + ((size_t)(b*12 + c+1)*32)*NN + n;
  float acc[32];
  #pragma unroll
  for (int o = 0; o < 32; ++o) acc[o] = bl[o];
  for (int i = 0; i < 32; ++i){
    float v0 = b2f(p0[(size_t)i*NN]);
    float v1 = b2f(p1[(size_t)i*NN]);
    #pragma unroll
    for (int o = 0; o < 32; ++o) acc[o] += v0*wl[o*64 + i*2] + v1*wl[o*64 + i*2 + 1];
  }
  unsigned short* op = yout + ((size_t)bt*32)*NN + n;
  #pragma unroll
  for (int o = 0; o < 32; ++o){ float v = acc[o]; op[(size_t)o*NN] = f2b(v > 0.f ? v : 0.f); }
}

// ---------------- tconv2 + relu + residual + LayerNorm + relu ----------------
__global__ void k_tail(const unsigned short* __restrict__ yp,   // [bt*32+i][NN] bf16
                       const void* __restrict__ x,              // original input, dtype per flag
                       const void* __restrict__ w2, const void* __restrict__ b2v,
                       const void* __restrict__ rw, const void* __restrict__ rbv,
                       const void* __restrict__ lng, const void* __restrict__ lnb,
                       void* __restrict__ out, const int* __restrict__ flagp){
  int flag = *flagp;
  __shared__ float wl[8*32*2];
  __shared__ float rl[8*16];
  __shared__ float bcv[8], rbc[8];
  __shared__ float redS[4*8], redS2[4*8];
  int tid = threadIdx.x;
  int bt = blockIdx.x, og = blockIdx.y, o0 = og*8;
  int b = bt / 12, t = bt % 12, c = (t == 0) ? 10 : (t - 1);
  for (int i = tid; i < 512; i += 256){ int oo = i >> 6, rem = i & 63; wl[i] = ld(w2, (o0 + oo)*64 + rem, flag); }
  for (int i = tid; i < 128; i += 256){ int oo = i >> 4, ii = i & 15; rl[i] = ld(rw, (o0 + oo)*16 + ii, flag); }
  if (tid < 8){ bcv[tid] = ld(b2v, o0 + tid, flag); rbc[tid] = ld(rbv, o0 + tid, flag); }
  __syncthreads();
  float acc[8][8];
  #pragma unroll
  for (int oo = 0; oo < 8; ++oo)
    #pragma unroll
    for (int nn = 0; nn < 8; ++nn) acc[oo][nn] = bcv[oo];
  const unsigned short* p0 = yp + ((size_t)(b*12 + c  )*32)*NN;
  const unsigned short* p1 = yp + ((size_t)(b*12 + c+1)*32)*NN;
  for (int i = 0; i < 32; ++i){
    float v0[8], v1[8];
    #pragma unroll
    for (int nn = 0; nn < 8; ++nn){
      int n = nn*256 + tid;
      v0[nn] = b2f(p0[(size_t)i*NN + n]);
      v1[nn] = b2f(p1[(size_t)i*NN + n]);
    }
    #pragma unroll
    for (int oo = 0; oo < 8; ++oo){
      float w0 = wl[oo*64 + i*2], w1 = wl[oo*64 + i*2 + 1];
      #pragma unroll
      for (int nn = 0; nn < 8; ++nn) acc[oo][nn] += v0[nn]*w0 + v1[nn]*w1;
    }
  }
  // xt = relu(conv2 out); then add residual bias
  #pragma unroll
  for (int oo = 0; oo < 8; ++oo)
    #pragma unroll
    for (int nn = 0; nn < 8; ++nn){ float v = acc[oo][nn]; acc[oo][nn] = (v > 0.f ? v : 0.f) + rbc[oo]; }
  size_t xbase = ((size_t)(b*12 + t)*16)*NN;
  for (int i = 0; i < 16; ++i){
    float xv[8];
    #pragma unroll
    for (int nn = 0; nn < 8; ++nn) xv[nn] = ld(x, xbase + (size_t)i*NN + nn*256 + tid, flag);
    #pragma unroll
    for (int oo = 0; oo < 8; ++oo){
      float r = rl[oo*16 + i];
      #pragma unroll
      for (int nn = 0; nn < 8; ++nn) acc[oo][nn] += xv[nn]*r;
    }
  }
  // LayerNorm over n per (b,t,o)
  int lane = tid & 63, wv = tid >> 6;
  #pragma unroll
  for (int oo = 0; oo < 8; ++oo){
    float s = 0.f, s2 = 0.f;
    #pragma unroll
    for (int nn = 0; nn < 8; ++nn){ float v = acc[oo][nn]; s += v; s2 += v*v; }
    for (int off = 32; off; off >>= 1){ s += __shfl_down(s, off); s2 += __shfl_down(s2, off); }
    if (lane == 0){ redS[wv*8 + oo] = s; redS2[wv*8 + oo] = s2; }
  }
  __syncthreads();
  float mu[8], inv[8];
  #pragma unroll
  for (int oo = 0; oo < 8; ++oo){
    float S  = redS [oo] + redS [8 + oo] + redS [16 + oo] + redS [24 + oo];
    float S2 = redS2[oo] + redS2[8 + oo] + redS2[16 + oo] + redS2[24 + oo];
    float m = S * (1.f/2048.f);
    float var = S2 * (1.f/2048.f) - m*m;
    mu[oo] = m; inv[oo] = rsqrtf(var + 1e-5f);
  }
  size_t obase = ((size_t)((b*12 + t)*32 + o0))*NN;
  #pragma unroll
  for (int nn = 0; nn < 8; ++nn){
    int n = nn*256 + tid;
    float g = ld(lng, n, flag), be = ld(lnb, n, flag);
    #pragma unroll
    for (int oo = 0; oo < 8; ++oo){
      float v = (acc[oo][nn] - mu[oo])*inv[oo]*g + be;
      v = v > 0.f ? v : 0.f;
      if (flag) ((unsigned short*)out)[obase + (size_t)oo*NN + n] = f2b(v);
      else      ((float*)out)[obase + (size_t)oo*NN + n] = v;
    }
  }
}

// ---------------- launcher ----------------
extern "C" void kernel_launch(void* const* d_in, const int* in_sizes, int n_in,
                              void* d_out, int out_size, void* d_ws, size_t ws_size,
                              hipStream_t stream){
  const void* x    = d_in[0];
  const void* cheb = d_in[1];
  const void* th1  = d_in[2];
  const void* th2  = d_in[3];
  const void* m1w  = d_in[4];
  const void* m1b  = d_in[5];
  const void* m2w  = d_in[6];
  const void* m2b  = d_in[7];
  const void* t1w  = d_in[8];
  const void* t1b  = d_in[9];
  const void* t2w  = d_in[10];
  const void* t2b  = d_in[11];
  const void* rw   = d_in[12];
  const void* rb   = d_in[13];
  const void* lng  = d_in[14];
  const void* lnb  = d_in[15];
  char* ws = (char*)d_ws;

  int*   flag  = (int*)ws;
  float* att0  = (float*)(ws + 4096);
  float* att   = (float*)(ws + 8192);
  unsigned short* X1 = (unsigned short*)(ws + 16384);
  unsigned short* Z  = (unsigned short*)(ws + 16384 + (size_t)M2*NN*2);
  unsigned short* X2 = (unsigned short*)d_out;   // bf16 scratch fits in d_out either dtype

  size_t fixed = 16384 + (size_t)M2*NN*2;
  int CH = 1024;                                 // z chunk col width; shrink to fit ws
  while (CH > 256 && fixed + (size_t)3*M2*2*CH > ws_size) CH >>= 1;
  int nch = NN / CH;

  k_sniff   <<<1, 64, 0, stream>>>((const unsigned short*)x, flag);
  k_att_mean<<<384, 256, 0, stream>>>(x, att0, flag);
  k_att_mlp <<<1, 64, 0, stream>>>(att0, m1w, m1b, m2w, m2b, att, flag);

  for (int ci = 0; ci < nch; ++ci){
    k_gemm_v<0><<<dim3(M1/16, CH/256, 3), 256, 0, stream>>>(x, att, cheb, Z, M1, ci*CH, CH, flag);
    k_mix<16><<<dim3(384, CH/128), 256, 0, stream>>>(Z, th1, X1, ci*CH, CH, flag);
  }
  for (int ci = 0; ci < nch; ++ci){
    k_gemm_v<1><<<dim3(M2/16, CH/256, 3), 256, 0, stream>>>(X1, att, cheb, Z, M2, ci*CH, CH, flag);
    k_mix<32><<<dim3(384, CH/128), 256, 0, stream>>>(Z, th2, X2, ci*CH, CH, flag);
  }
  k_tconv1<<<dim3(384, 8), 256, 0, stream>>>(X2, t1w, t1b, X1, flag);   // Y1 reuses X1
  k_tail  <<<dim3(384, 4), 256, 0, stream>>>(X1, x, t2w, t2b, rw, rb, lng, lnb, d_out, flag);
}

// Round 4
// 2442.449 us; speedup vs baseline: 5.3522x; 5.3522x over previous
//
#include <hip/hip_runtime.h>

#define DI __device__ __forceinline__

typedef __attribute__((ext_vector_type(8))) short short8;   // 8 bf16 (guide-verified MFMA frag type)
typedef __attribute__((ext_vector_type(4))) float f32x4;

static constexpr int Bb  = 32;
static constexpr int Tt  = 12;
static constexpr int FIN = 16;
static constexpr int NN  = 2048;
static constexpr int HID = 3;
static constexpr int M1  = Bb*Tt*FIN;    // 6144
static constexpr int M2  = Bb*Tt*32;     // 12288

DI float b2f(unsigned short u){
  unsigned int v = ((unsigned int)u) << 16;
  float f; __builtin_memcpy(&f, &v, 4); return f;
}
DI unsigned short f2b(float f){
  unsigned int v; __builtin_memcpy(&v, &f, 4);
  v = v + 0x7FFFu + ((v >> 16) & 1u);
  return (unsigned short)(v >> 16);
}
DI float ld(const void* p, size_t i, int flag){
  return flag ? b2f(((const unsigned short*)p)[i]) : ((const float*)p)[i];
}

// ---------------- dtype sniff ----------------
__global__ void k_sniff(const unsigned short* __restrict__ x, int* __restrict__ flag){
  int tid = threadIdx.x;
  float v = b2f(x[tid*2]);
  int bad = (!(v == v)) || (fabsf(v) > 1e6f);
  unsigned long long m = __ballot(bad);
  if (tid == 0) *flag = (m == 0ull) ? 1 : 0;
}

// ---------------- convert big tensors to guaranteed-bf16 (copy if already bf16) ----
__global__ void k_convert(const void* __restrict__ src, unsigned short* __restrict__ dst,
                          long long n8, const int* __restrict__ flagp){
  int flag = *flagp;
  long long i = (long long)blockIdx.x*256 + threadIdx.x;
  if (i >= n8) return;
  size_t base = (size_t)i * 8;
  if (flag){
    *(uint4*)(dst + base) = *(const uint4*)((const unsigned short*)src + base);
  } else {
    const float* f = (const float*)src + base;
    unsigned short o[8];
    #pragma unroll
    for (int j = 0; j < 8; ++j) o[j] = f2b(f[j]);
    uint4 ov; __builtin_memcpy(&ov, o, 16);
    *(uint4*)(dst + base) = ov;
  }
}

// ---------------- SE attention ----------------
__global__ void k_att_mean(const void* __restrict__ x, float* __restrict__ att0,
                           const int* __restrict__ flagp){
  int flag = *flagp;
  int bt = blockIdx.x; int tid = threadIdx.x;
  size_t base = (size_t)bt * FIN * NN;
  float s = 0.f;
  for (int i = tid; i < FIN*NN; i += 256) s += ld(x, base + i, flag);
  for (int off = 32; off; off >>= 1) s += __shfl_down(s, off);
  __shared__ float red[4];
  if ((tid & 63) == 0) red[tid >> 6] = s;
  __syncthreads();
  if (tid == 0) att0[bt] = (red[0]+red[1]+red[2]+red[3]) * (1.f / (FIN*NN));
}

__global__ void k_att_mlp(const float* __restrict__ att0,
                          const void* __restrict__ m1w, const void* __restrict__ m1b,
                          const void* __restrict__ m2w, const void* __restrict__ m2b,
                          float* __restrict__ att, const int* __restrict__ flagp){
  int flag = *flagp;
  int b = threadIdx.x;
  if (b >= Bb) return;
  float a[Tt];
  #pragma unroll
  for (int t = 0; t < Tt; ++t) a[t] = att0[b*Tt + t];
  float h[HID];
  #pragma unroll
  for (int j = 0; j < HID; ++j){
    float s = ld(m1b, j, flag);
    #pragma unroll
    for (int t = 0; t < Tt; ++t) s += a[t] * ld(m1w, j*Tt + t, flag);
    h[j] = s > 0.f ? s : 0.f;
  }
  #pragma unroll
  for (int t = 0; t < Tt; ++t){
    float s = ld(m2b, t, flag);
    #pragma unroll
    for (int j = 0; j < HID; ++j) s += h[j] * ld(m2w, t*HID + j, flag);
    att[b*Tt + t] = 1.f / (1.f + expf(-s));
  }
}

// ---------------- MFMA GEMM: z[k][m][col] = sum_kk A[m][kk] * cheb[k+1][col][kk]
// (cheb symmetric; k=0 identity plane skipped). 64x128 tile, 2 cheb planes/block,
// KK=64 staged panels, XOR-16B-block LDS swizzle.
template <int SCALE>
__global__ __launch_bounds__(256, 2)
void k_gemm(const unsigned short* __restrict__ Ag,
            const float* __restrict__ att,
            const unsigned short* __restrict__ chb,
            unsigned short* __restrict__ z,
            int M, int n0, int CH){
  __shared__ __align__(16) unsigned short As[64*64];
  __shared__ __align__(16) unsigned short Bs[2*128*64];
  int tid  = threadIdx.x;
  int w    = tid >> 6, lane = tid & 63, q = lane >> 4, cc = lane & 15;
  int row0 = blockIdx.x * 64;
  int gn0  = n0 + blockIdx.y * 128;

  f32x4 zero4 = {0.f, 0.f, 0.f, 0.f};
  f32x4 acc[2][4][2];
  #pragma unroll
  for (int k = 0; k < 2; ++k)
    #pragma unroll
    for (int mt = 0; mt < 4; ++mt)
      #pragma unroll
      for (int ns = 0; ns < 2; ++ns) acc[k][mt][ns] = zero4;

  for (int it = 0; it < 32; ++it){
    int kk0 = it * 64;
    uint4 ra[2], rb[8];
    #pragma unroll
    for (int p = 0; p < 2; ++p){
      int s = tid + p*256;                 // A slot: 64 rows x 8 blocks of 8 bf16
      int r = s >> 3, j = s & 7;
      ra[p] = *(const uint4*)(Ag + (size_t)(row0 + r)*NN + kk0 + ((j ^ (r & 7)) << 3));
      if (SCALE){
        float sc = att[(row0 + r) >> 4];
        unsigned short sp[8]; __builtin_memcpy(sp, &ra[p], 16);
        #pragma unroll
        for (int i = 0; i < 8; ++i) sp[i] = f2b(b2f(sp[i]) * sc);
        __builtin_memcpy(&ra[p], sp, 16);
      }
    }
    #pragma unroll
    for (int p = 0; p < 8; ++p){
      int s = tid + p*256;                 // B slot: 2 planes x 128 rows x 8 blocks
      int k = s >> 10, rem = s & 1023, r = rem >> 3, j = rem & 7;
      rb[p] = *(const uint4*)(chb + (size_t)(k + 1)*NN*NN + (size_t)(gn0 + r)*NN + kk0 + ((j ^ (r & 7)) << 3));
    }
    __syncthreads();                       // previous iteration's compute done
    #pragma unroll
    for (int p = 0; p < 2; ++p){ int s = tid + p*256; *(uint4*)(As + (s << 3)) = ra[p]; }
    #pragma unroll
    for (int p = 0; p < 8; ++p){ int s = tid + p*256; *(uint4*)(Bs + (s << 3)) = rb[p]; }
    __syncthreads();                       // staging visible
    #pragma unroll
    for (int st = 0; st < 2; ++st){
      short8 af[4];
      #pragma unroll
      for (int mt = 0; mt < 4; ++mt)
        af[mt] = *(const short8*)(As + ((mt*16 + cc) << 6) + ((((st << 2) + q) ^ (cc & 7)) << 3));
      #pragma unroll
      for (int k = 0; k < 2; ++k){
        #pragma unroll
        for (int ns = 0; ns < 2; ++ns){
          int r = w*32 + ns*16 + cc;       // (r&7) == (cc&7)
          short8 bv = *(const short8*)(Bs + (((k << 7) + r) << 6) + ((((st << 2) + q) ^ (cc & 7)) << 3));
          #pragma unroll
          for (int mt = 0; mt < 4; ++mt)
            acc[k][mt][ns] = __builtin_amdgcn_mfma_f32_16x16x32_bf16(af[mt], bv, acc[k][mt][ns], 0, 0, 0);
        }
      }
    }
  }
  // epilogue: C/D layout col = lane&15, row = q*4 + r  [verified m89/m91]
  #pragma unroll
  for (int k = 0; k < 2; ++k)
    #pragma unroll
    for (int mt = 0; mt < 4; ++mt)
      #pragma unroll
      for (int ns = 0; ns < 2; ++ns){
        int col = blockIdx.y*128 + w*32 + ns*16 + cc;   // chunk-local
        f32x4 v = acc[k][mt][ns];
        #pragma unroll
        for (int r = 0; r < 4; ++r){
          int row = row0 + mt*16 + q*4 + r;
          z[((size_t)(k*M + row))*CH + col] = f2b(v[r]);
        }
      }
}

// ---------------- theta mixing (k=0 identity term read from src directly)
// xg[bt][o][n] = relu( sum_f theta[0][f][o]*src[bt*F+f][n]*sc + sum_{k=1,2} theta[k][f][o]*z[k-1][...] )
template <int F, int SCALE>
__global__ void k_mix(const unsigned short* __restrict__ z,
                      const unsigned short* __restrict__ src,
                      const float* __restrict__ att,
                      const void* __restrict__ theta,
                      unsigned short* __restrict__ xg,
                      int n0, int CH, const int* __restrict__ flagp){
  int flag = *flagp;
  __shared__ float th[3*F*32];
  int tid = threadIdx.x;
  int bt  = blockIdx.x;
  int colb = blockIdx.y * 128;
  for (int i = tid; i < 3*F*32; i += 256) th[i] = ld(theta, i, flag);
  __syncthreads();
  int col = tid & 127, oh = tid >> 7;
  int gcol = n0 + colb + col;
  const int M = 384*F;
  float sc = SCALE ? att[bt] : 1.f;
  float acc[16];
  #pragma unroll
  for (int o = 0; o < 16; ++o) acc[o] = 0.f;
  for (int f = 0; f < F; ++f){
    float zv = b2f(src[(size_t)(bt*F + f)*NN + gcol]) * sc;
    const float* tp = &th[f*32 + oh*16];
    #pragma unroll
    for (int o = 0; o < 16; ++o) acc[o] += zv * tp[o];
  }
  for (int k = 1; k < 3; ++k)
    for (int f = 0; f < F; ++f){
      float zv = b2f(z[((size_t)((k-1)*M + bt*F + f))*CH + colb + col]);
      const float* tp = &th[(k*F + f)*32 + oh*16];
      #pragma unroll
      for (int o = 0; o < 16; ++o) acc[o] += zv * tp[o];
    }
  #pragma unroll
  for (int o = 0; o < 16; ++o){
    float v = acc[o]; v = v > 0.f ? v : 0.f;
    xg[((size_t)(bt*32 + oh*16 + o))*NN + gcol] = f2b(v);
  }
}

// ---------------- temporal conv 1 (kernel (1,2), wrap-pad, relu) ----------------
__global__ void k_tconv1(const unsigned short* __restrict__ xin,
                         const void* __restrict__ wgt, const void* __restrict__ bias,
                         unsigned short* __restrict__ yout, const int* __restrict__ flagp){
  int flag = *flagp;
  __shared__ float wl[32*32*2];
  __shared__ float bl[32];
  int tid = threadIdx.x;
  for (int i = tid; i < 2048; i += 256) wl[i] = ld(wgt, i, flag);
  if (tid < 32) bl[tid] = ld(bias, tid, flag);
  __syncthreads();
  int bt = blockIdx.x, b = bt / 12, t = bt % 12;
  int c = (t == 0) ? 10 : (t - 1);
  int n = blockIdx.y*256 + tid;
  const unsigned short* p0 = xin + ((size_t)(b*12 + c  )*32)*NN + n;
  const unsigned short* p1 = xin + ((size_t)(b*12 + c+1)*32)*NN + n;
  float acc[32];
  #pragma unroll
  for (int o = 0; o < 32; ++o) acc[o] = bl[o];
  for (int i = 0; i < 32; ++i){
    float v0 = b2f(p0[(size_t)i*NN]);
    float v1 = b2f(p1[(size_t)i*NN]);
    #pragma unroll
    for (int o = 0; o < 32; ++o) acc[o] += v0*wl[o*64 + i*2] + v1*wl[o*64 + i*2 + 1];
  }
  unsigned short* op = yout + ((size_t)bt*32)*NN + n;
  #pragma unroll
  for (int o = 0; o < 32; ++o){ float v = acc[o]; op[(size_t)o*NN] = f2b(v > 0.f ? v : 0.f); }
}

// ---------------- tconv2 + relu + residual + LayerNorm + relu ----------------
__global__ void k_tail(const unsigned short* __restrict__ yp,
                       const void* __restrict__ x,
                       const void* __restrict__ w2, const void* __restrict__ b2v,
                       const void* __restrict__ rw, const void* __restrict__ rbv,
                       const void* __restrict__ lng, const void* __restrict__ lnb,
                       void* __restrict__ out, const int* __restrict__ flagp){
  int flag = *flagp;
  __shared__ float wl[8*32*2];
  __shared__ float rl[8*16];
  __shared__ float bcv[8], rbc[8];
  __shared__ float redS[4*8], redS2[4*8];
  int tid = threadIdx.x;
  int bt = blockIdx.x, og = blockIdx.y, o0 = og*8;
  int b = bt / 12, t = bt % 12, c = (t == 0) ? 10 : (t - 1);
  for (int i = tid; i < 512; i += 256){ int oo = i >> 6, rem = i & 63; wl[i] = ld(w2, (o0 + oo)*64 + rem, flag); }
  for (int i = tid; i < 128; i += 256){ int oo = i >> 4, ii = i & 15; rl[i] = ld(rw, (o0 + oo)*16 + ii, flag); }
  if (tid < 8){ bcv[tid] = ld(b2v, o0 + tid, flag); rbc[tid] = ld(rbv, o0 + tid, flag); }
  __syncthreads();
  float acc[8][8];
  #pragma unroll
  for (int oo = 0; oo < 8; ++oo)
    #pragma unroll
    for (int nn = 0; nn < 8; ++nn) acc[oo][nn] = bcv[oo];
  const unsigned short* p0 = yp + ((size_t)(b*12 + c  )*32)*NN;
  const unsigned short* p1 = yp + ((size_t)(b*12 + c+1)*32)*NN;
  for (int i = 0; i < 32; ++i){
    float v0[8], v1[8];
    #pragma unroll
    for (int nn = 0; nn < 8; ++nn){
      int n = nn*256 + tid;
      v0[nn] = b2f(p0[(size_t)i*NN + n]);
      v1[nn] = b2f(p1[(size_t)i*NN + n]);
    }
    #pragma unroll
    for (int oo = 0; oo < 8; ++oo){
      float w0 = wl[oo*64 + i*2], w1 = wl[oo*64 + i*2 + 1];
      #pragma unroll
      for (int nn = 0; nn < 8; ++nn) acc[oo][nn] += v0[nn]*w0 + v1[nn]*w1;
    }
  }
  #pragma unroll
  for (int oo = 0; oo < 8; ++oo)
    #pragma unroll
    for (int nn = 0; nn < 8; ++nn){ float v = acc[oo][nn]; acc[oo][nn] = (v > 0.f ? v : 0.f) + rbc[oo]; }
  size_t xbase = ((size_t)(b*12 + t)*16)*NN;
  for (int i = 0; i < 16; ++i){
    float xv[8];
    #pragma unroll
    for (int nn = 0; nn < 8; ++nn) xv[nn] = ld(x, xbase + (size_t)i*NN + nn*256 + tid, flag);
    #pragma unroll
    for (int oo = 0; oo < 8; ++oo){
      float r = rl[oo*16 + i];
      #pragma unroll
      for (int nn = 0; nn < 8; ++nn) acc[oo][nn] += xv[nn]*r;
    }
  }
  int lane = tid & 63, wv = tid >> 6;
  #pragma unroll
  for (int oo = 0; oo < 8; ++oo){
    float s = 0.f, s2 = 0.f;
    #pragma unroll
    for (int nn = 0; nn < 8; ++nn){ float v = acc[oo][nn]; s += v; s2 += v*v; }
    for (int off = 32; off; off >>= 1){ s += __shfl_down(s, off); s2 += __shfl_down(s2, off); }
    if (lane == 0){ redS[wv*8 + oo] = s; redS2[wv*8 + oo] = s2; }
  }
  __syncthreads();
  float mu[8], inv[8];
  #pragma unroll
  for (int oo = 0; oo < 8; ++oo){
    float S  = redS [oo] + redS [8 + oo] + redS [16 + oo] + redS [24 + oo];
    float S2 = redS2[oo] + redS2[8 + oo] + redS2[16 + oo] + redS2[24 + oo];
    float m = S * (1.f/2048.f);
    float var = S2 * (1.f/2048.f) - m*m;
    mu[oo] = m; inv[oo] = rsqrtf(var + 1e-5f);
  }
  size_t obase = ((size_t)((b*12 + t)*32 + o0))*NN;
  #pragma unroll
  for (int nn = 0; nn < 8; ++nn){
    int n = nn*256 + tid;
    float g = ld(lng, n, flag), be = ld(lnb, n, flag);
    #pragma unroll
    for (int oo = 0; oo < 8; ++oo){
      float v = (acc[oo][nn] - mu[oo])*inv[oo]*g + be;
      v = v > 0.f ? v : 0.f;
      if (flag) ((unsigned short*)out)[obase + (size_t)oo*NN + n] = f2b(v);
      else      ((float*)out)[obase + (size_t)oo*NN + n] = v;
    }
  }
}

// ---------------- launcher ----------------
extern "C" void kernel_launch(void* const* d_in, const int* in_sizes, int n_in,
                              void* d_out, int out_size, void* d_ws, size_t ws_size,
                              hipStream_t stream){
  const void* x    = d_in[0];
  const void* cheb = d_in[1];
  const void* th1  = d_in[2];
  const void* th2  = d_in[3];
  const void* m1w  = d_in[4];
  const void* m1b  = d_in[5];
  const void* m2w  = d_in[6];
  const void* m2b  = d_in[7];
  const void* t1w  = d_in[8];
  const void* t1b  = d_in[9];
  const void* t2w  = d_in[10];
  const void* t2b  = d_in[11];
  const void* rw   = d_in[12];
  const void* rb   = d_in[13];
  const void* lng  = d_in[14];
  const void* lnb  = d_in[15];
  char* ws = (char*)d_ws;

  int*   flag  = (int*)ws;
  float* att0  = (float*)(ws + 4096);
  float* att   = (float*)(ws + 8192);
  unsigned short* xb  = (unsigned short*)(ws + 16384);                       // x as bf16, 25.2 MB
  unsigned short* chb = xb + (size_t)M1*NN;                                  // cheb as bf16, 25.2 MB
  unsigned short* X1  = chb + (size_t)3*NN*NN;                               // 50.3 MB
  unsigned short* Z   = X1 + (size_t)M2*NN;                                  // 2-plane z chunk
  unsigned short* X2  = (unsigned short*)d_out;                              // bf16 scratch in d_out

  size_t fixed = 16384 + (size_t)M1*NN*2 + (size_t)3*NN*NN*2 + (size_t)M2*NN*2;  // ~100.7 MB
  int CH = 1024;                                  // z chunk col width; shrink to fit ws
  while (CH > 128 && fixed + (size_t)2*M2*2*CH > ws_size) CH >>= 1;
  int nch = NN / CH;

  k_sniff  <<<1, 64, 0, stream>>>((const unsigned short*)x, flag);
  k_convert<<<((long long)M1*NN/8 + 255)/256, 256, 0, stream>>>(x, xb, (long long)M1*NN/8, flag);
  k_convert<<<((long long)3*NN*NN/8 + 255)/256, 256, 0, stream>>>(cheb, chb, (long long)3*NN*NN/8, flag);
  k_att_mean<<<384, 256, 0, stream>>>(x, att0, flag);
  k_att_mlp <<<1, 64, 0, stream>>>(att0, m1w, m1b, m2w, m2b, att, flag);

  for (int ci = 0; ci < nch; ++ci){
    k_gemm<1><<<dim3(M1/64, CH/128), 256, 0, stream>>>(xb, att, chb, Z, M1, ci*CH, CH);
    k_mix<16,1><<<dim3(384, CH/128), 256, 0, stream>>>(Z, xb, att, th1, X1, ci*CH, CH, flag);
  }
  for (int ci = 0; ci < nch; ++ci){
    k_gemm<0><<<dim3(M2/64, CH/128), 256, 0, stream>>>(X1, att, chb, Z, M2, ci*CH, CH);
    k_mix<32,0><<<dim3(384, CH/128), 256, 0, stream>>>(Z, X1, att, th2, X2, ci*CH, CH, flag);
  }
  k_tconv1<<<dim3(384, 8), 256, 0, stream>>>(X2, t1w, t1b, X1, flag);
  k_tail  <<<dim3(384, 4), 256, 0, stream>>>(X1, x, t2w, t2b, rw, rb, lng, lnb, d_out, flag);
}

// Round 5
// 1391.289 us; speedup vs baseline: 9.3960x; 1.7555x over previous
//
#include <hip/hip_runtime.h>

#define DI __device__ __forceinline__

typedef __attribute__((ext_vector_type(8))) short short8;   // 8 bf16 (round-4-verified MFMA frag type)
typedef __attribute__((ext_vector_type(4))) float f32x4;

static constexpr int Bb  = 32;
static constexpr int Tt  = 12;
static constexpr int FIN = 16;
static constexpr int NN  = 2048;
static constexpr int HID = 3;
static constexpr int M1  = Bb*Tt*FIN;    // 6144
static constexpr int M2  = Bb*Tt*32;     // 12288

DI float b2f(unsigned short u){
  unsigned int v = ((unsigned int)u) << 16;
  float f; __builtin_memcpy(&f, &v, 4); return f;
}
DI unsigned short f2b(float f){
  unsigned int v; __builtin_memcpy(&v, &f, 4);
  v = v + 0x7FFFu + ((v >> 16) & 1u);
  return (unsigned short)(v >> 16);
}
DI float ld(const void* p, size_t i, int flag){
  return flag ? b2f(((const unsigned short*)p)[i]) : ((const float*)p)[i];
}

// ---------------- dtype sniff ----------------
__global__ void k_sniff(const unsigned short* __restrict__ x, int* __restrict__ flag){
  int tid = threadIdx.x;
  float v = b2f(x[tid*2]);
  int bad = (!(v == v)) || (fabsf(v) > 1e6f);
  unsigned long long m = __ballot(bad);
  if (tid == 0) *flag = (m == 0ull) ? 1 : 0;
}

// ---------------- convert to guaranteed-bf16 (src element offset `off`) ----------------
__global__ void k_convert(const void* __restrict__ src, unsigned short* __restrict__ dst,
                          long long n8, const int* __restrict__ flagp, long long off){
  int flag = *flagp;
  long long i = (long long)blockIdx.x*256 + threadIdx.x;
  if (i >= n8) return;
  size_t base = (size_t)i * 8;
  if (flag){
    *(uint4*)(dst + base) = *(const uint4*)((const unsigned short*)src + off + base);
  } else {
    const float* f = (const float*)src + off + base;
    unsigned short o[8];
    #pragma unroll
    for (int j = 0; j < 8; ++j) o[j] = f2b(f[j]);
    uint4 ov; __builtin_memcpy(&ov, o, 16);
    *(uint4*)(dst + base) = ov;
  }
}

// ---------------- SE attention ----------------
__global__ void k_att_mean(const void* __restrict__ x, float* __restrict__ att0,
                           const int* __restrict__ flagp){
  int flag = *flagp;
  int bt = blockIdx.x; int tid = threadIdx.x;
  size_t base = (size_t)bt * FIN * NN;
  float s = 0.f;
  for (int i = tid; i < FIN*NN; i += 256) s += ld(x, base + i, flag);
  for (int off = 32; off; off >>= 1) s += __shfl_down(s, off);
  __shared__ float red[4];
  if ((tid & 63) == 0) red[tid >> 6] = s;
  __syncthreads();
  if (tid == 0) att0[bt] = (red[0]+red[1]+red[2]+red[3]) * (1.f / (FIN*NN));
}

__global__ void k_att_mlp(const float* __restrict__ att0,
                          const void* __restrict__ m1w, const void* __restrict__ m1b,
                          const void* __restrict__ m2w, const void* __restrict__ m2b,
                          float* __restrict__ att, const int* __restrict__ flagp){
  int flag = *flagp;
  int b = threadIdx.x;
  if (b >= Bb) return;
  float a[Tt];
  #pragma unroll
  for (int t = 0; t < Tt; ++t) a[t] = att0[b*Tt + t];
  float h[HID];
  #pragma unroll
  for (int j = 0; j < HID; ++j){
    float s = ld(m1b, j, flag);
    #pragma unroll
    for (int t = 0; t < Tt; ++t) s += a[t] * ld(m1w, j*Tt + t, flag);
    h[j] = s > 0.f ? s : 0.f;
  }
  #pragma unroll
  for (int t = 0; t < Tt; ++t){
    float s = ld(m2b, t, flag);
    #pragma unroll
    for (int j = 0; j < HID; ++j) s += h[j] * ld(m2w, t*HID + j, flag);
    att[b*Tt + t] = 1.f / (1.f + expf(-s));
  }
}

// ---------------- fused gconv: X[bt*32+o][n] = relu( sum_{kk} theta_T[o][kk] * zfull[kk][n] )
// zfull rows: [0,F) identity (A itself, att-scaled if SCALE), [F,2F) A@cheb1^T, [2F,3F) A@cheb2^T.
// Main loop: 128x128 tile MFMA GEMM over 2 cheb planes (cheb symmetric, B rows = output cols).
// Epilogue: per-wave LDS repack of z column-strip into B-fragment layout + theta^T MFMA mix.
template <int SCALE, int F>
__global__ __launch_bounds__(256, 2)
void k_gemm(const unsigned short* __restrict__ Ag,
            const float* __restrict__ att,
            const unsigned short* __restrict__ chb,   // planes 1,2 only: [2][NN][NN]
            const void* __restrict__ theta,           // [3][F][32], dtype per flag
            unsigned short* __restrict__ X,           // out [bt*32+o][NN] bf16
            const int* __restrict__ flagp){
  constexpr int Kp = (F == 16) ? 64 : 96;     // zero-padded K for the mix MFMA
  constexpr int PP = (F == 16) ? 72 : 104;    // LDS pitch (16B-multiple, bank-spread)
  constexpr int G  = 128 / F;                 // bt-groups per 128-row tile
  constexpr int NKB = Kp / 32;

  __shared__ __align__(16) unsigned short SMEM[3*128*64];  // 48 KB: As|Bs, reused as zs
  __shared__ __align__(16) unsigned short TT[32*PP];       // theta^T bf16 [o][kk]

  int flag = *flagp;
  int tid  = threadIdx.x;
  int w    = tid >> 6, lane = tid & 63, q = lane >> 4, cc = lane & 15;
  int row0 = blockIdx.x * 128;
  int gn0  = blockIdx.y * 128;

  // stage theta^T (zero-padded)
  for (int idx = tid; idx < 32*PP; idx += 256){
    int o = idx / PP, kk = idx % PP;
    float v = (kk < 3*F) ? ld(theta, (size_t)kk*32 + o, flag) : 0.f;
    TT[idx] = f2b(v);
  }

  unsigned short* As = SMEM;             // [128][64]
  unsigned short* Bs = SMEM + 128*64;    // [2][128][64]

  f32x4 zero4 = {0.f, 0.f, 0.f, 0.f};
  f32x4 acc[2][8][2];
  #pragma unroll
  for (int k = 0; k < 2; ++k)
    #pragma unroll
    for (int mt = 0; mt < 8; ++mt)
      #pragma unroll
      for (int ns = 0; ns < 2; ++ns) acc[k][mt][ns] = zero4;

  for (int it = 0; it < 32; ++it){
    int kk0 = it * 64;
    uint4 ra[4], rb[8];
    #pragma unroll
    for (int p = 0; p < 4; ++p){
      int s = tid + p*256;                 // A: 128 rows x 8 blocks of 8 bf16
      int r = s >> 3, j = s & 7;
      ra[p] = *(const uint4*)(Ag + (size_t)(row0 + r)*NN + kk0 + ((j ^ (r & 7)) << 3));
      if (SCALE){
        float sc = att[(row0 + r) >> 4];
        unsigned short sp[8]; __builtin_memcpy(sp, &ra[p], 16);
        #pragma unroll
        for (int i = 0; i < 8; ++i) sp[i] = f2b(b2f(sp[i]) * sc);
        __builtin_memcpy(&ra[p], sp, 16);
      }
    }
    #pragma unroll
    for (int p = 0; p < 8; ++p){
      int s = tid + p*256;                 // B: 2 planes x 128 rows x 8 blocks
      int k = s >> 10, rem = s & 1023, r = rem >> 3, j = rem & 7;
      rb[p] = *(const uint4*)(chb + (size_t)k*NN*NN + (size_t)(gn0 + r)*NN + kk0 + ((j ^ (r & 7)) << 3));
    }
    __syncthreads();
    #pragma unroll
    for (int p = 0; p < 4; ++p){ int s = tid + p*256; *(uint4*)(As + (s << 3)) = ra[p]; }
    #pragma unroll
    for (int p = 0; p < 8; ++p){ int s = tid + p*256; *(uint4*)(Bs + (s << 3)) = rb[p]; }
    __syncthreads();
    #pragma unroll
    for (int st = 0; st < 2; ++st){
      short8 af[8];
      #pragma unroll
      for (int mt = 0; mt < 8; ++mt)
        af[mt] = *(const short8*)(As + ((mt*16 + cc) << 6) + ((((st << 2) + q) ^ (cc & 7)) << 3));
      #pragma unroll
      for (int k = 0; k < 2; ++k){
        #pragma unroll
        for (int ns = 0; ns < 2; ++ns){
          int r = w*32 + ns*16 + cc;       // (r&7) == (cc&7)
          short8 bv = *(const short8*)(Bs + (((k << 7) + r) << 6) + ((((st << 2) + q) ^ (cc & 7)) << 3));
          #pragma unroll
          for (int mt = 0; mt < 8; ++mt)
            acc[k][mt][ns] = __builtin_amdgcn_mfma_f32_16x16x32_bf16(af[mt], bv, acc[k][mt][ns], 0, 0, 0);
        }
      }
    }
  }

  __syncthreads();   // main-loop LDS reads done; SMEM free for reuse; TT visible

  // ---- epilogue: wave-private z repack + theta^T MFMA mix ----
  unsigned short* zs = SMEM + w * (32*PP);   // [32 cols][PP]

  short8 afm[2][NKB];
  #pragma unroll
  for (int mt_o = 0; mt_o < 2; ++mt_o)
    #pragma unroll
    for (int kb = 0; kb < NKB; ++kb)
      afm[mt_o][kb] = *(const short8*)(TT + (mt_o*16 + cc)*PP + kb*32 + q*8);

  if (F == 16){                              // zero rows [48,64) once
    if (lane < 32){
      #pragma unroll
      for (int j = 0; j < 4; ++j) *(uint2*)(zs + lane*PP + 48 + j*4) = make_uint2(0u, 0u);
    }
  }

  int bt0 = row0 / F;
  #pragma unroll
  for (int g = 0; g < G; ++g){
    float sc = SCALE ? att[bt0 + g] : 1.f;
    // identity rows [0,F): zs[col][f] = Ag[row0+g*F+f][gn0 + w*32 + col] (scaled)
    #pragma unroll
    for (int pass = 0; pass < F/16; ++pass){
      int rf = pass*16 + (lane >> 2), c8 = (lane & 3) * 8;
      uint4 u = *(const uint4*)(Ag + (size_t)(row0 + g*F + rf)*NN + gn0 + w*32 + c8);
      unsigned short sp[8]; __builtin_memcpy(sp, &u, 16);
      #pragma unroll
      for (int e = 0; e < 8; ++e){
        unsigned short val = SCALE ? f2b(b2f(sp[e]) * sc) : sp[e];
        zs[(c8 + e)*PP + rf] = val;
      }
    }
    // plane rows [F,3F) from acc
    #pragma unroll
    for (int k = 0; k < 2; ++k)
      #pragma unroll
      for (int mt_l = 0; mt_l < F/16; ++mt_l)
        #pragma unroll
        for (int ns = 0; ns < 2; ++ns){
          int mt = g*(F/16) + mt_l;
          f32x4 v = acc[k][mt][ns];
          #pragma unroll
          for (int r = 0; r < 4; ++r)
            zs[(ns*16 + cc)*PP + F*(k+1) + mt_l*16 + q*4 + r] = f2b(v[r]);
        }
    // mix MFMA: out[o][col] = sum_kk TT[o][kk] * zs[col][kk]
    #pragma unroll
    for (int mt_o = 0; mt_o < 2; ++mt_o)
      #pragma unroll
      for (int ch = 0; ch < 2; ++ch){
        f32x4 am = zero4;
        #pragma unroll
        for (int kb = 0; kb < NKB; ++kb){
          short8 bm = *(const short8*)(zs + (ch*16 + cc)*PP + kb*32 + q*8);
          am = __builtin_amdgcn_mfma_f32_16x16x32_bf16(afm[mt_o][kb], bm, am, 0, 0, 0);
        }
        #pragma unroll
        for (int r = 0; r < 4; ++r){
          int o = mt_o*16 + q*4 + r;
          float v = am[r]; v = v > 0.f ? v : 0.f;
          X[((size_t)((bt0 + g)*32 + o))*NN + gn0 + w*32 + ch*16 + cc] = f2b(v);
        }
      }
  }
}

// ---------------- temporal conv 1 (kernel (1,2), wrap-pad, relu) ----------------
__global__ void k_tconv1(const unsigned short* __restrict__ xin,
                         const void* __restrict__ wgt, const void* __restrict__ bias,
                         unsigned short* __restrict__ yout, const int* __restrict__ flagp){
  int flag = *flagp;
  __shared__ float wl[32*32*2];
  __shared__ float bl[32];
  int tid = threadIdx.x;
  for (int i = tid; i < 2048; i += 256) wl[i] = ld(wgt, i, flag);
  if (tid < 32) bl[tid] = ld(bias, tid, flag);
  __syncthreads();
  int bt = blockIdx.x, b = bt / 12, t = bt % 12;
  int c = (t == 0) ? 10 : (t - 1);
  int n = blockIdx.y*256 + tid;
  const unsigned short* p0 = xin + ((size_t)(b*12 + c  )*32)*NN + n;
  const unsigned short* p1 = xin + ((size_t)(b*12 + c+1)*32)*NN + n;
  float acc[32];
  #pragma unroll
  for (int o = 0; o < 32; ++o) acc[o] = bl[o];
  for (int i = 0; i < 32; ++i){
    float v0 = b2f(p0[(size_t)i*NN]);
    float v1 = b2f(p1[(size_t)i*NN]);
    #pragma unroll
    for (int o = 0; o < 32; ++o) acc[o] += v0*wl[o*64 + i*2] + v1*wl[o*64 + i*2 + 1];
  }
  unsigned short* op = yout + ((size_t)bt*32)*NN + n;
  #pragma unroll
  for (int o = 0; o < 32; ++o){ float v = acc[o]; op[(size_t)o*NN] = f2b(v > 0.f ? v : 0.f); }
}

// ---------------- tconv2 + relu + residual + LayerNorm + relu ----------------
__global__ void k_tail(const unsigned short* __restrict__ yp,
                       const void* __restrict__ x,
                       const void* __restrict__ w2, const void* __restrict__ b2v,
                       const void* __restrict__ rw, const void* __restrict__ rbv,
                       const void* __restrict__ lng, const void* __restrict__ lnb,
                       void* __restrict__ out, const int* __restrict__ flagp){
  int flag = *flagp;
  __shared__ float wl[8*32*2];
  __shared__ float rl[8*16];
  __shared__ float bcv[8], rbc[8];
  __shared__ float redS[4*8], redS2[4*8];
  int tid = threadIdx.x;
  int bt = blockIdx.x, og = blockIdx.y, o0 = og*8;
  int b = bt / 12, t = bt % 12, c = (t == 0) ? 10 : (t - 1);
  for (int i = tid; i < 512; i += 256){ int oo = i >> 6, rem = i & 63; wl[i] = ld(w2, (o0 + oo)*64 + rem, flag); }
  for (int i = tid; i < 128; i += 256){ int oo = i >> 4, ii = i & 15; rl[i] = ld(rw, (o0 + oo)*16 + ii, flag); }
  if (tid < 8){ bcv[tid] = ld(b2v, o0 + tid, flag); rbc[tid] = ld(rbv, o0 + tid, flag); }
  __syncthreads();
  float acc[8][8];
  #pragma unroll
  for (int oo = 0; oo < 8; ++oo)
    #pragma unroll
    for (int nn = 0; nn < 8; ++nn) acc[oo][nn] = bcv[oo];
  const unsigned short* p0 = yp + ((size_t)(b*12 + c  )*32)*NN;
  const unsigned short* p1 = yp + ((size_t)(b*12 + c+1)*32)*NN;
  for (int i = 0; i < 32; ++i){
    float v0[8], v1[8];
    #pragma unroll
    for (int nn = 0; nn < 8; ++nn){
      int n = nn*256 + tid;
      v0[nn] = b2f(p0[(size_t)i*NN + n]);
      v1[nn] = b2f(p1[(size_t)i*NN + n]);
    }
    #pragma unroll
    for (int oo = 0; oo < 8; ++oo){
      float w0 = wl[oo*64 + i*2], w1 = wl[oo*64 + i*2 + 1];
      #pragma unroll
      for (int nn = 0; nn < 8; ++nn) acc[oo][nn] += v0[nn]*w0 + v1[nn]*w1;
    }
  }
  #pragma unroll
  for (int oo = 0; oo < 8; ++oo)
    #pragma unroll
    for (int nn = 0; nn < 8; ++nn){ float v = acc[oo][nn]; acc[oo][nn] = (v > 0.f ? v : 0.f) + rbc[oo]; }
  size_t xbase = ((size_t)(b*12 + t)*16)*NN;
  for (int i = 0; i < 16; ++i){
    float xv[8];
    #pragma unroll
    for (int nn = 0; nn < 8; ++nn) xv[nn] = ld(x, xbase + (size_t)i*NN + nn*256 + tid, flag);
    #pragma unroll
    for (int oo = 0; oo < 8; ++oo){
      float r = rl[oo*16 + i];
      #pragma unroll
      for (int nn = 0; nn < 8; ++nn) acc[oo][nn] += xv[nn]*r;
    }
  }
  int lane = tid & 63, wv = tid >> 6;
  #pragma unroll
  for (int oo = 0; oo < 8; ++oo){
    float s = 0.f, s2 = 0.f;
    #pragma unroll
    for (int nn = 0; nn < 8; ++nn){ float v = acc[oo][nn]; s += v; s2 += v*v; }
    for (int off = 32; off; off >>= 1){ s += __shfl_down(s, off); s2 += __shfl_down(s2, off); }
    if (lane == 0){ redS[wv*8 + oo] = s; redS2[wv*8 + oo] = s2; }
  }
  __syncthreads();
  float mu[8], inv[8];
  #pragma unroll
  for (int oo = 0; oo < 8; ++oo){
    float S  = redS [oo] + redS [8 + oo] + redS [16 + oo] + redS [24 + oo];
    float S2 = redS2[oo] + redS2[8 + oo] + redS2[16 + oo] + redS2[24 + oo];
    float m = S * (1.f/2048.f);
    float var = S2 * (1.f/2048.f) - m*m;
    mu[oo] = m; inv[oo] = rsqrtf(var + 1e-5f);
  }
  size_t obase = ((size_t)((b*12 + t)*32 + o0))*NN;
  #pragma unroll
  for (int nn = 0; nn < 8; ++nn){
    int n = nn*256 + tid;
    float g = ld(lng, n, flag), be = ld(lnb, n, flag);
    #pragma unroll
    for (int oo = 0; oo < 8; ++oo){
      float v = (acc[oo][nn] - mu[oo])*inv[oo]*g + be;
      v = v > 0.f ? v : 0.f;
      if (flag) ((unsigned short*)out)[obase + (size_t)oo*NN + n] = f2b(v);
      else      ((float*)out)[obase + (size_t)oo*NN + n] = v;
    }
  }
}

// ---------------- launcher ----------------
extern "C" void kernel_launch(void* const* d_in, const int* in_sizes, int n_in,
                              void* d_out, int out_size, void* d_ws, size_t ws_size,
                              hipStream_t stream){
  const void* x    = d_in[0];
  const void* cheb = d_in[1];
  const void* th1  = d_in[2];
  const void* th2  = d_in[3];
  const void* m1w  = d_in[4];
  const void* m1b  = d_in[5];
  const void* m2w  = d_in[6];
  const void* m2b  = d_in[7];
  const void* t1w  = d_in[8];
  const void* t1b  = d_in[9];
  const void* t2w  = d_in[10];
  const void* t2b  = d_in[11];
  const void* rw   = d_in[12];
  const void* rb   = d_in[13];
  const void* lng  = d_in[14];
  const void* lnb  = d_in[15];
  char* ws = (char*)d_ws;

  int*   flag  = (int*)ws;
  float* att0  = (float*)(ws + 4096);
  float* att   = (float*)(ws + 8192);
  unsigned short* xb  = (unsigned short*)(ws + 16384);        // x bf16: 25.2 MB
  unsigned short* chb = xb + (size_t)M1*NN;                   // cheb planes 1,2 bf16: 16.8 MB
  unsigned short* X1  = chb + (size_t)2*NN*NN;                // gconv1 out: 50.3 MB
  unsigned short* X2  = (unsigned short*)d_out;               // gconv2 out (bf16 scratch in d_out)
  unsigned short* Y1  = X1;                                   // tconv1 out reuses X1

  k_sniff  <<<1, 64, 0, stream>>>((const unsigned short*)x, flag);
  k_convert<<<((long long)M1*NN/8 + 255)/256, 256, 0, stream>>>(x, xb, (long long)M1*NN/8, flag, 0);
  k_convert<<<((long long)2*NN*NN/8 + 255)/256, 256, 0, stream>>>(cheb, chb, (long long)2*NN*NN/8, flag, (long long)NN*NN);
  k_att_mean<<<384, 256, 0, stream>>>(x, att0, flag);
  k_att_mlp <<<1, 64, 0, stream>>>(att0, m1w, m1b, m2w, m2b, att, flag);

  k_gemm<1,16><<<dim3(M1/128, 16), 256, 0, stream>>>(xb, att, chb, th1, X1, flag);
  k_gemm<0,32><<<dim3(M2/128, 16), 256, 0, stream>>>(X1, att, chb, th2, X2, flag);

  k_tconv1<<<dim3(384, 8), 256, 0, stream>>>(X2, t1w, t1b, Y1, flag);
  k_tail  <<<dim3(384, 4), 256, 0, stream>>>(Y1, x, t2w, t2b, rw, rb, lng, lnb, d_out, flag);
}